// Round 1
// 1734.141 us; speedup vs baseline: 1.5502x; 1.5502x over previous
//
#include <hip/hip_runtime.h>
#include <hip/hip_bf16.h>

#define NN 256
#define CCH 512
#define TT 4
#define SS 64
#define LL 256

typedef unsigned short u16;
typedef unsigned int u32;

typedef __bf16 bf16_t;
typedef bf16_t bf16x8 __attribute__((ext_vector_type(8)));
typedef float f32x16 __attribute__((ext_vector_type(16)));

__device__ __forceinline__ float bf2f(u32 h){
    return __uint_as_float(h << 16);
}
__device__ __forceinline__ u16 f2bf(float f){
    u32 u = __float_as_uint(f);
    u32 r = u + 0x7fffu + ((u >> 16) & 1u);
    return (u16)(r >> 16);
}
__device__ __forceinline__ bf16x8 ldg8(const u16* p){
    uint4 q = *(const uint4*)p;          // 16B aligned by construction
    return __builtin_bit_cast(bf16x8, q);
}
__device__ __forceinline__ bf16x8 ldl8(const u16* p){
    uint2 a = *(const uint2*)p;          // 8B aligned (stride 36 u16 = 72 B)
    uint2 b = *(const uint2*)(p + 4);
    uint4 q; q.x = a.x; q.y = a.y; q.z = b.x; q.w = b.y;
    return __builtin_bit_cast(bf16x8, q);
}

// ---------------------------------------------------------------------------
// Weight transpose: W[o][c][tap] fp32  ->  Wt[((tap*32 + c/16)*512 + o)*16 + c%16] bf16
// ---------------------------------------------------------------------------
__global__ __launch_bounds__(256) void wt_kernel(
    const float* __restrict__ W, u16* __restrict__ Wt)
{
    const int e = blockIdx.x * 256 + threadIdx.x;     // 0 .. 9*32*512*16-1
    const int cl  = e & 15;
    const int o   = (e >> 4) & 511;
    const int cg  = (e >> 13) & 31;
    const int tap = e >> 18;
    Wt[e] = f2bf(W[((size_t)o * CCH + cg * 16 + cl) * 9 + tap]);
}

// ---------------------------------------------------------------------------
// Implicit-GEMM conv via MFMA 32x32x16 bf16.  (unchanged from prior round)
// ---------------------------------------------------------------------------
__global__ __launch_bounds__(256, 2) void conv_mfma_kernel(
    const float* __restrict__ x, const u16* __restrict__ Wt, u16* __restrict__ outb)
{
    __shared__ u16 lds[4 * 100 * 36];     // 28.8 KB
    const int tid = threadIdx.x;
    const int n  = blockIdx.x;
    const int ob = blockIdx.y * 128;
    const int lane = tid & 63;
    const int w  = tid >> 6;
    const int wm = w & 1, wn = w >> 1;
    const int h   = lane >> 5;
    const int col = lane & 31;
    const int r  = col >> 3, cc = col & 7;

    for (int i = tid; i < 7200; i += 256) ((u32*)lds)[i] = 0;   // borders = conv padding

    f32x16 acc[2][4];
    #pragma unroll
    for (int m = 0; m < 2; ++m)
      #pragma unroll
      for (int j = 0; j < 4; ++j)
        #pragma unroll
        for (int e = 0; e < 16; ++e) acc[m][j][e] = 0.f;

    const int cp2 = tid >> 4;          // c-pair 0..15
    const int s4  = (tid & 15) << 2;   // spatial 0,4,..,60

    int bbase[4];
    #pragma unroll
    for (int j = 0; j < 4; ++j){
        const int nt = wn * 4 + j;
        const int p = nt >> 1, sh = nt & 1;
        bbase[j] = (p * 100 + (sh * 4 + r) * 10 + cc) * 36 + h * 8;
    }
    const size_t abase = (size_t)(ob + wm * 64 + col) * 16 + h * 8;

    for (int ch = 0; ch < 16; ++ch){
        const int c0 = ch * 32;
        __syncthreads();
        #pragma unroll
        for (int p = 0; p < 4; ++p){
            const float* xr = x + (((size_t)n * CCH + c0 + 2 * cp2) * TT + p) * SS + s4;
            const float4 v0 = *(const float4*)xr;
            const float4 v1 = *(const float4*)(xr + 256);   // next c row (TT*SS floats)
            const float a0[4] = {v0.x, v0.y, v0.z, v0.w};
            const float a1[4] = {v1.x, v1.y, v1.z, v1.w};
            #pragma unroll
            for (int i = 0; i < 4; ++i){
                const int s = s4 + i;
                const int sp = ((s >> 3) + 1) * 10 + (s & 7) + 1;
                ((u32*)lds)[(p * 100 + sp) * 18 + cp2] =
                    (u32)f2bf(a0[i]) | ((u32)f2bf(a1[i]) << 16);
            }
        }
        __syncthreads();
        #pragma unroll
        for (int tap = 0; tap < 9; ++tap){
            const int tof = ((tap / 3) * 10 + (tap % 3)) * 36;
            #pragma unroll
            for (int ks = 0; ks < 2; ++ks){
                const size_t ai = (size_t)(tap * 32 + ch * 2 + ks) * 8192 + abase;
                const bf16x8 a0 = ldg8(Wt + ai);
                const bf16x8 a1 = ldg8(Wt + ai + 512);
                bf16x8 bfr[4];
                #pragma unroll
                for (int j = 0; j < 4; ++j)
                    bfr[j] = ldl8(&lds[bbase[j] + tof + ks * 16]);
                #pragma unroll
                for (int j = 0; j < 4; ++j){
                    acc[0][j] = __builtin_amdgcn_mfma_f32_32x32x16_bf16(a0, bfr[j], acc[0][j], 0, 0, 0);
                    acc[1][j] = __builtin_amdgcn_mfma_f32_32x32x16_bf16(a1, bfr[j], acc[1][j], 0, 0, 0);
                }
            }
        }
    }

    #pragma unroll
    for (int m = 0; m < 2; ++m){
        #pragma unroll
        for (int j = 0; j < 4; ++j){
            const int nt = wn * 4 + j;
            const int p = nt >> 1, sh = nt & 1;
            const int loc = p * SS + sh * 32 + col;
            u16* orow = outb + ((size_t)loc * NN + n) * CCH + ob + wm * 64 + m * 32;
            #pragma unroll
            for (int g2 = 0; g2 < 4; ++g2){
                uint2 val;
                val.x = (u32)f2bf(acc[m][j][g2 * 4 + 0]) | ((u32)f2bf(acc[m][j][g2 * 4 + 1]) << 16);
                val.y = (u32)f2bf(acc[m][j][g2 * 4 + 2]) | ((u32)f2bf(acc[m][j][g2 * 4 + 3]) << 16);
                *(uint2*)&orow[g2 * 8 + h * 4] = val;
            }
        }
    }
}

// ---------------------------------------------------------------------------
// conv_out: GN+affine+ReLU staging; epilogue adds residual. (unchanged)
// ---------------------------------------------------------------------------
__global__ __launch_bounds__(256, 2) void conv_out_mfma_kernel(
    const u16* __restrict__ virtb, const u16* __restrict__ Wt,
    const float* __restrict__ x, const float* __restrict__ gamma,
    const float* __restrict__ beta, const float* __restrict__ musig,
    float* __restrict__ out)
{
    __shared__ u16 lds[4 * 100 * 36];
    const int tid = threadIdx.x;
    const int n  = blockIdx.x;
    const int ob = blockIdx.y * 128;
    const int lane = tid & 63;
    const int w  = tid >> 6;
    const int wm = w & 1, wn = w >> 1;
    const int h   = lane >> 5;
    const int col = lane & 31;
    const int r  = col >> 3, cc = col & 7;

    const float mu   = musig[2 * n];
    const float rsig = musig[2 * n + 1];

    for (int i = tid; i < 7200; i += 256) ((u32*)lds)[i] = 0;

    f32x16 acc[2][4];
    #pragma unroll
    for (int m = 0; m < 2; ++m)
      #pragma unroll
      for (int j = 0; j < 4; ++j)
        #pragma unroll
        for (int e = 0; e < 16; ++e) acc[m][j][e] = 0.f;

    const int cp = tid & 15;        // c-pair (coalesced in [loc][n][c])
    const int sg = tid >> 4;        // 0..15

    int bbase[4];
    #pragma unroll
    for (int j = 0; j < 4; ++j){
        const int nt = wn * 4 + j;
        const int p = nt >> 1, sh = nt & 1;
        bbase[j] = (p * 100 + (sh * 4 + r) * 10 + cc) * 36 + h * 8;
    }
    const size_t abase = (size_t)(ob + wm * 64 + col) * 16 + h * 8;

    for (int ch = 0; ch < 16; ++ch){
        const int c0 = ch * 32;
        const float g0 = gamma[c0 + 2 * cp], g1 = gamma[c0 + 2 * cp + 1];
        const float b0 = beta [c0 + 2 * cp], b1 = beta [c0 + 2 * cp + 1];
        __syncthreads();
        #pragma unroll
        for (int p = 0; p < 4; ++p){
            #pragma unroll
            for (int i = 0; i < 4; ++i){
                const int s = sg * 4 + i;
                const u32 wv = *(const u32*)(virtb + ((size_t)(p * SS + s) * NN + n) * CCH + c0 + 2 * cp);
                const float f0 = fmaxf((bf2f(wv & 0xffffu) - mu) * rsig * g0 + b0, 0.f);
                const float f1 = fmaxf((bf2f(wv >> 16)     - mu) * rsig * g1 + b1, 0.f);
                const int sp = ((s >> 3) + 1) * 10 + (s & 7) + 1;
                ((u32*)lds)[(p * 100 + sp) * 18 + cp] =
                    (u32)f2bf(f0) | ((u32)f2bf(f1) << 16);
            }
        }
        __syncthreads();
        #pragma unroll
        for (int tap = 0; tap < 9; ++tap){
            const int tof = ((tap / 3) * 10 + (tap % 3)) * 36;
            #pragma unroll
            for (int ks = 0; ks < 2; ++ks){
                const size_t ai = (size_t)(tap * 32 + ch * 2 + ks) * 8192 + abase;
                const bf16x8 a0 = ldg8(Wt + ai);
                const bf16x8 a1 = ldg8(Wt + ai + 512);
                bf16x8 bfr[4];
                #pragma unroll
                for (int j = 0; j < 4; ++j)
                    bfr[j] = ldl8(&lds[bbase[j] + tof + ks * 16]);
                #pragma unroll
                for (int j = 0; j < 4; ++j){
                    acc[0][j] = __builtin_amdgcn_mfma_f32_32x32x16_bf16(a0, bfr[j], acc[0][j], 0, 0, 0);
                    acc[1][j] = __builtin_amdgcn_mfma_f32_32x32x16_bf16(a1, bfr[j], acc[1][j], 0, 0, 0);
                }
            }
        }
    }

    #pragma unroll
    for (int m = 0; m < 2; ++m){
        #pragma unroll
        for (int j = 0; j < 4; ++j){
            const int nt = wn * 4 + j;
            const int p = nt >> 1, sh = nt & 1;
            const int s = sh * 32 + col;
            #pragma unroll
            for (int g2 = 0; g2 < 4; ++g2){
                const int o0 = ob + wm * 64 + m * 32 + 8 * g2 + 4 * h;
                #pragma unroll
                for (int rr = 0; rr < 4; ++rr){
                    const size_t oi = (((size_t)n * CCH + o0 + rr) * TT + p) * SS + s;
                    out[oi] = x[oi] + acc[m][j][g2 * 4 + rr];
                }
            }
        }
    }
}

// ---------------------------------------------------------------------------
// V transpose: vb [loc][n][c] -> vt [loc][c][n]  (bf16, 64x64 LDS tiles,
// XOR col-block swizzle keyed on (row&7)^((row>>3)&7) so the strided read
// phase spreads across banks).
// ---------------------------------------------------------------------------
__global__ __launch_bounds__(256) void vt_kernel(
    const u16* __restrict__ vb, u16* __restrict__ vt)
{
    __shared__ u16 ts[64][72];
    const int loc = blockIdx.x;
    const int n0 = (blockIdx.y & 3) * 64;
    const int c0 = (blockIdx.y >> 2) * 64;
    const int tid = threadIdx.x;
    const int rr = tid >> 3;          // 0..31
    const int ct = tid & 7;           // col-block / n-block
    #pragma unroll
    for (int q = 0; q < 2; ++q){
        const int row = rr + q * 32;
        const int key = (row & 7) ^ ((row >> 3) & 7);
        const uint4 v = *(const uint4*)(vb + ((size_t)loc * NN + n0 + row) * CCH + c0 + ct * 8);
        *(uint4*)&ts[row][(ct ^ key) << 3] = v;
    }
    __syncthreads();
    #pragma unroll
    for (int q = 0; q < 2; ++q){
        const int c = rr + q * 32;    // local c row of vt
        u16 tmp[8];
        #pragma unroll
        for (int e = 0; e < 8; ++e){
            const int n = ct * 8 + e;
            const int key = (n & 7) ^ ((n >> 3) & 7);   // = e ^ ct
            tmp[e] = ts[n][(((c >> 3) ^ key) << 3) + (c & 7)];
        }
        uint4 o;
        o.x = (u32)tmp[0] | ((u32)tmp[1] << 16);
        o.y = (u32)tmp[2] | ((u32)tmp[3] << 16);
        o.z = (u32)tmp[4] | ((u32)tmp[5] << 16);
        o.w = (u32)tmp[6] | ((u32)tmp[7] << 16);
        *(uint4*)(vt + ((size_t)loc * CCH + c0 + c) * NN + n0 + ct * 8) = o;
    }
}

// ---------------------------------------------------------------------------
// MFMA attention.  Block = (loc, 32-row i-tile), 4 waves.
//  block-id swizzle: a loc's 8 i-tile blocks land on the SAME XCD, adjacent
//  in dispatch order, so K/V (512 KB/loc) stay in that XCD's L2.
//  Phase 1: S = Q K^T  (direct 16B global frag loads, no LDS staging)
//  Phase 2: masked softmax over j in LDS (8 threads/row), P -> frag-layout LDS
//  Phase 3: out = P V   (A from LDS frags, B from vt, contiguous 16B loads)
// ---------------------------------------------------------------------------
__global__ __launch_bounds__(256, 3) void attn_mfma_kernel(
    const u16* __restrict__ qb, const u16* __restrict__ kb,
    const u16* __restrict__ vt, const int* __restrict__ roi,
    u16* __restrict__ virtb)
{
    __shared__ float Srow[32][264];      // 33.8 KB, stride 66 granules (==2 mod 8)
    __shared__ u16 Pfrag[16 * 64 * 8];   // 16 KB, A-frag layout for PV
    __shared__ int roi_s[256];

    const int bid = blockIdx.x;
    const int loc = ((bid >> 6) << 3) | (bid & 7);   // XCD-coherent decode
    const int it  = (bid >> 3) & 7;
    const int i0  = it * 32;
    const int tid = threadIdx.x;
    const int lane = tid & 63;
    const int w   = tid >> 6;
    const int h   = lane >> 5;
    const int col = lane & 31;

    roi_s[tid] = roi[tid];

    // ---- Phase 1: QK^T, wave w owns j = w*64 .. w*64+63 ----
    f32x16 acc0, acc1;
    #pragma unroll
    for (int e = 0; e < 16; ++e){ acc0[e] = 0.f; acc1[e] = 0.f; }

    const u16* qp = qb + ((size_t)loc * NN + i0 + col) * CCH + h * 8;
    const u16* kp = kb + ((size_t)loc * NN + w * 64 + col) * CCH + h * 8;

    #pragma unroll 4
    for (int kc = 0; kc < 32; ++kc){
        const bf16x8 a  = ldg8(qp + kc * 16);
        const bf16x8 b0 = ldg8(kp + kc * 16);
        const bf16x8 b1 = ldg8(kp + 32 * CCH + kc * 16);
        acc0 = __builtin_amdgcn_mfma_f32_32x32x16_bf16(a, b0, acc0, 0, 0, 0);
        acc1 = __builtin_amdgcn_mfma_f32_32x32x16_bf16(a, b1, acc1, 0, 0, 0);
    }

    #pragma unroll
    for (int e = 0; e < 16; ++e){
        const int r = (e & 3) + 8 * (e >> 2) + 4 * h;
        Srow[r][w * 64 + col]      = acc0[e];
        Srow[r][w * 64 + 32 + col] = acc1[e];
    }
    __syncthreads();

    // ---- Phase 2: masked softmax, 8 threads per row, j strided by 32 ----
    {
        const int row = tid >> 3, u = tid & 7;
        const int myroi = roi_s[i0 + row];
        const float scale = 0.04419417382415922f;
        float ev[32];
        float mx = -1e30f;
        #pragma unroll
        for (int g = 0; g < 8; ++g){
            const float4 s4 = *(const float4*)&Srow[row][u * 4 + g * 32];
            const float ss[4] = {s4.x, s4.y, s4.z, s4.w};
            #pragma unroll
            for (int q = 0; q < 4; ++q){
                const int j = u * 4 + g * 32 + q;
                const float xv = (roi_s[j] == myroi) ? ss[q] * scale : -1e30f;
                ev[g * 4 + q] = xv;
                mx = fmaxf(mx, xv);
            }
        }
        mx = fmaxf(mx, __shfl_xor(mx, 1));
        mx = fmaxf(mx, __shfl_xor(mx, 2));
        mx = fmaxf(mx, __shfl_xor(mx, 4));
        float ssum = 0.f;
        #pragma unroll
        for (int q2 = 0; q2 < 32; ++q2){
            const float e2 = (ev[q2] > -1e29f) ? __expf(ev[q2] - mx) : 0.f;
            ev[q2] = e2;
            ssum += e2;
        }
        ssum += __shfl_xor(ssum, 1);
        ssum += __shfl_xor(ssum, 2);
        ssum += __shfl_xor(ssum, 4);
        const float rinv = 1.f / ssum;
        // write P in A-frag layout: entry (t,half,row,e) <-> j = t*16+half*8+e
        #pragma unroll
        for (int g = 0; g < 8; ++g){
            const int t    = 2 * g + (u >> 2);
            const int half = (u >> 1) & 1;
            const int e0   = (u & 1) * 4;
            uint2 pw;
            pw.x = (u32)f2bf(ev[g * 4 + 0] * rinv) | ((u32)f2bf(ev[g * 4 + 1] * rinv) << 16);
            pw.y = (u32)f2bf(ev[g * 4 + 2] * rinv) | ((u32)f2bf(ev[g * 4 + 3] * rinv) << 16);
            *(uint2*)&Pfrag[((t * 64 + half * 32 + row) << 3) + e0] = pw;
        }
    }
    __syncthreads();

    // ---- Phase 3: PV, wave w owns c = w*128 .. w*128+127 ----
    f32x16 pacc[4];
    #pragma unroll
    for (int jn = 0; jn < 4; ++jn)
        #pragma unroll
        for (int e = 0; e < 16; ++e) pacc[jn][e] = 0.f;

    const u16* vp = vt + ((size_t)loc * CCH + w * 128 + col) * NN + h * 8;
    #pragma unroll 2
    for (int t = 0; t < 16; ++t){
        const bf16x8 pa = ldg8(&Pfrag[(t * 64 + lane) << 3]);   // ds_read_b128, conflict-free
        #pragma unroll
        for (int jn = 0; jn < 4; ++jn){
            const bf16x8 bv = ldg8(vp + (size_t)(jn * 32) * NN + t * 16);
            pacc[jn] = __builtin_amdgcn_mfma_f32_32x32x16_bf16(pa, bv, pacc[jn], 0, 0, 0);
        }
    }

    u16* op = virtb + ((size_t)loc * NN + i0) * CCH + w * 128 + col;
    #pragma unroll
    for (int jn = 0; jn < 4; ++jn){
        #pragma unroll
        for (int e = 0; e < 16; ++e){
            const int r = (e & 3) + 8 * (e >> 2) + 4 * h;
            op[(size_t)r * CCH + jn * 32] = f2bf(pacc[jn][e]);
        }
    }
}

// ---------------------------------------------------------------------------
// GroupNorm stats per sample.
// ---------------------------------------------------------------------------
__global__ __launch_bounds__(256) void stats_kernel(
    const u16* __restrict__ virtb, float* __restrict__ musig)
{
    const int n = blockIdx.x;
    const int tid = threadIdx.x;
    float s = 0.f, q = 0.f;
    for (int loc = 0; loc < LL; ++loc){
        const u32 v = *(const u32*)(virtb + ((size_t)loc * NN + n) * CCH + 2 * tid);
        const float a = bf2f(v & 0xffffu);
        const float b = bf2f(v >> 16);
        s += a + b;
        q += a * a + b * b;
    }
    #pragma unroll
    for (int off = 1; off < 64; off <<= 1){
        s += __shfl_xor(s, off);
        q += __shfl_xor(q, off);
    }
    __shared__ float red[8];
    const int wave = tid >> 6;
    if ((tid & 63) == 0){ red[wave * 2] = s; red[wave * 2 + 1] = q; }
    __syncthreads();
    if (tid == 0){
        const float S = red[0] + red[2] + red[4] + red[6];
        const float Q = red[1] + red[3] + red[5] + red[7];
        const float inv = 1.f / 131072.f;
        const float mval = S * inv;
        const float var = Q * inv - mval * mval;
        musig[2 * n]     = mval;
        musig[2 * n + 1] = rsqrtf(var + 1e-5f);
    }
}

__global__ void sentinel_kernel(float* out){
    const size_t i = (size_t)blockIdx.x * 256 + threadIdx.x;
    out[i] = 1.0e9f;
}

extern "C" void kernel_launch(void* const* d_in, const int* in_sizes, int n_in,
                              void* d_out, int out_size, void* d_ws, size_t ws_size,
                              hipStream_t stream)
{
    (void)in_sizes; (void)n_in; (void)out_size;
    const float* x   = (const float*)d_in[0];
    const int*   roi = (const int*)d_in[1];
    const float* Wq  = (const float*)d_in[2];
    const float* Wk  = (const float*)d_in[3];
    const float* Wv  = (const float*)d_in[4];
    const float* Wc  = (const float*)d_in[5];
    const float* gam = (const float*)d_in[6];
    const float* bet = (const float*)d_in[7];
    float* out = (float*)d_out;

    const size_t EL = 33554432ull;                 // N*C*T*H*W
    const size_t need = EL * 2ull * 4ull + 2048ull;
    if (ws_size < need){
        sentinel_kernel<<<131072, 256, 0, stream>>>(out);
        return;
    }
    u16* qb    = (u16*)d_ws;
    u16* kb    = qb + EL;
    u16* vb    = kb + EL;
    u16* virtb = vb + EL;
    float* musig = (float*)(virtb + EL);

    // Scratch inside d_out (134 MB): WtA at [0, 4.7 MB), vt at [8 MB, 75 MB).
    // Both dead by the time conv_out writes out (stream order serializes).
    u16* WtA = (u16*)d_out;
    u16* vt  = (u16*)d_out + (1u << 22);   // byte offset 8 MB
    u16* WtC = qb;                          // qb is dead after attn

    const dim3 cgrid(256, 4);

    wt_kernel<<<9216, 256, 0, stream>>>(Wq, WtA);
    conv_mfma_kernel<<<cgrid, 256, 0, stream>>>(x, WtA, qb);
    wt_kernel<<<9216, 256, 0, stream>>>(Wk, WtA);
    conv_mfma_kernel<<<cgrid, 256, 0, stream>>>(x, WtA, kb);
    wt_kernel<<<9216, 256, 0, stream>>>(Wv, WtA);
    conv_mfma_kernel<<<cgrid, 256, 0, stream>>>(x, WtA, vb);

    vt_kernel<<<dim3(256, 32), 256, 0, stream>>>(vb, vt);
    attn_mfma_kernel<<<2048, 256, 0, stream>>>(qb, kb, vt, roi, virtb);
    stats_kernel<<<256, 256, 0, stream>>>(virtb, musig);

    wt_kernel<<<9216, 256, 0, stream>>>(Wc, WtC);
    conv_out_mfma_kernel<<<cgrid, 256, 0, stream>>>(virtb, WtC, x, gam, bet, musig, out);
}